// Round 4
// baseline (536.155 us; speedup 1.0000x reference)
//
#include <hip/hip_runtime.h>
#include <stdint.h>
#include <math.h>

typedef unsigned short u16;
typedef __attribute__((ext_vector_type(4))) float f32x4;
typedef __attribute__((ext_vector_type(8))) short bf16x8;

__device__ __forceinline__ u16 f2bf(float f) {
  uint32_t u = __float_as_uint(f);
  u += 0x7FFFu + ((u >> 16) & 1u);
  return (u16)(u >> 16);
}

__device__ __forceinline__ void async16(const void* g, void* l) {
  __builtin_amdgcn_global_load_lds(
      (const __attribute__((address_space(1))) void*)g,
      (__attribute__((address_space(3))) void*)l, 16, 0, 0);
}

// ---------------- dequant / cast ----------------
__global__ void dequant4(const int4* __restrict__ q, ushort4* __restrict__ o, int n4,
                         const float* __restrict__ s, const int* __restrict__ z) {
  int i = blockIdx.x * 256 + threadIdx.x;
  if (i >= n4) return;
  const float sv = s[0];
  const int zv = z[0];
  int4 v = q[i];
  ushort4 r;
  r.x = f2bf(sv * (float)(v.x - zv));
  r.y = f2bf(sv * (float)(v.y - zv));
  r.z = f2bf(sv * (float)(v.z - zv));
  r.w = f2bf(sv * (float)(v.w - zv));
  o[i] = r;
}

__global__ void castx4(const float4* __restrict__ x, ushort4* __restrict__ o, int n4) {
  int i = blockIdx.x * 256 + threadIdx.x;
  if (i >= n4) return;
  float4 v = x[i];
  ushort4 r;
  r.x = f2bf(v.x); r.y = f2bf(v.y); r.z = f2bf(v.z); r.w = f2bf(v.w);
  o[i] = r;
}

// ---------------- BT GEMM: C[M,N] = A[M,K] * B[N,K]^T, 128x128 tile, BK=64 ----------------
// EPI 0: qkv scatter (q,k -> [B,H,T,D]; v -> [B,H,D,T]) with bias dequant
// EPI 1: fp32 out [M,N] with bias dequant
template <int EPI>
__global__ __launch_bounds__(256, 2) void gemm_bt(
    const u16* __restrict__ A, const u16* __restrict__ B, int K, int N,
    const int* __restrict__ bq, const float* __restrict__ bs, const int* __restrict__ bz,
    u16* __restrict__ qb, u16* __restrict__ kb, u16* __restrict__ vT,
    float* __restrict__ out) {
  __shared__ uint8_t sA[16384];  // 128 rows x 64 bf16, 8x16B chunks, chunk c stored at c^(row&7)
  __shared__ uint8_t sB[16384];
  const int tid = threadIdx.x;
  const int wave = tid >> 6, lane = tid & 63;
  const int quad = lane >> 4, l16 = lane & 15;
  const int wm = wave >> 1, wn = wave & 1;
  const int Mb = blockIdx.y << 7, Nb = blockIdx.x << 7;

  const u16* ag[4];
  const u16* bg[4];
  int lo[4];
#pragma unroll
  for (int i = 0; i < 4; ++i) {
    int row = wave * 32 + i * 8 + (lane >> 3);
    int c = (lane & 7) ^ (row & 7);
    ag[i] = A + (size_t)(Mb + row) * K + c * 8;
    bg[i] = B + (size_t)(Nb + row) * K + c * 8;
    lo[i] = wave * 4096 + i * 1024 + lane * 16;
  }

  f32x4 acc[4][4] = {};

  for (int kk = 0; kk < K; kk += 64) {
    __syncthreads();
#pragma unroll
    for (int i = 0; i < 4; ++i) {
      async16(ag[i] + kk, sA + lo[i]);
      async16(bg[i] + kk, sB + lo[i]);
    }
    __syncthreads();
#pragma unroll
    for (int ks = 0; ks < 2; ++ks) {
      bf16x8 af[4], bfr[4];
#pragma unroll
      for (int t = 0; t < 4; ++t) {
        int m = wm * 64 + t * 16 + l16;
        af[t] = *(const bf16x8*)(sA + m * 128 + ((((ks << 2) + quad) ^ (m & 7)) << 4));
        int n = wn * 64 + t * 16 + l16;
        bfr[t] = *(const bf16x8*)(sB + n * 128 + ((((ks << 2) + quad) ^ (n & 7)) << 4));
      }
#pragma unroll
      for (int mt = 0; mt < 4; ++mt)
#pragma unroll
        for (int nt = 0; nt < 4; ++nt)
          acc[mt][nt] = __builtin_amdgcn_mfma_f32_16x16x32_bf16(af[mt], bfr[nt], acc[mt][nt], 0, 0, 0);
    }
  }

  const float sbv = bs[0];
  const int zbv = bz[0];
#pragma unroll
  for (int nt = 0; nt < 4; ++nt) {
    const int o = Nb + wn * 64 + nt * 16 + l16;
    const float bias = sbv * (float)(bq[o] - zbv);
    if (EPI == 0) {
      const int which = o >> 11;
      const int cc = o & 2047;
      const int h = cc >> 7, d = cc & 127;
#pragma unroll
      for (int mt = 0; mt < 4; ++mt) {
        const int m0 = Mb + wm * 64 + mt * 16 + quad * 4;
        const int bi = m0 >> 10, t0 = m0 & 1023;
        const size_t bhx = (size_t)bi * 16 + h;
        if (which == 2) {
          ushort4 pv;
          pv.x = f2bf(acc[mt][nt][0] + bias);
          pv.y = f2bf(acc[mt][nt][1] + bias);
          pv.z = f2bf(acc[mt][nt][2] + bias);
          pv.w = f2bf(acc[mt][nt][3] + bias);
          *(ushort4*)(vT + (bhx * 128 + d) * 1024 + t0) = pv;
        } else {
          u16* dst = (which == 0 ? qb : kb) + (bhx * 1024 + t0) * 128 + d;
#pragma unroll
          for (int r = 0; r < 4; ++r) dst[r * 128] = f2bf(acc[mt][nt][r] + bias);
        }
      }
    } else {
#pragma unroll
      for (int mt = 0; mt < 4; ++mt) {
        const int m0 = Mb + wm * 64 + mt * 16 + quad * 4;
#pragma unroll
        for (int r = 0; r < 4; ++r)
          out[(size_t)(m0 + r) * N + o] = acc[mt][nt][r] + bias;
      }
    }
  }
}

// ---------------- flash attention: q-tile 128, kv-tile 128, Q in regs ----------------
__global__ __launch_bounds__(256, 2) void attn_fwd(
    const u16* __restrict__ qg, const u16* __restrict__ kg,
    const u16* __restrict__ vg, u16* __restrict__ yb) {
  __shared__ uint8_t smem[65536];
  uint8_t* sKP = smem;          // Q-stage / K-tile / P alias: 128 rows x 256B, chunk c at c^(row&15)
  uint8_t* sV = smem + 32768;   // V^T tile: 128 d-rows x 128 t, same swizzle
  const int tid = threadIdx.x;
  const int wave = tid >> 6, lane = tid & 63;
  const int quad = lane >> 4, l16 = lane & 15;
  // causal load balance: pair blocks so co-resident work sums ~constant
  const int qi = ((blockIdx.y >> 5) & 1) ? (7 - (int)blockIdx.x) : (int)blockIdx.x;
  const int bh = blockIdx.y;
  const int qbase = qi << 7;
  const size_t base = (size_t)bh << 17;  // *1024*128
  const u16* Q = qg + base;
  const u16* Kp = kg + base;
  const u16* Vp = vg + base;

  // stage Q tile -> sKP, then pull fragments to registers
#pragma unroll
  for (int i = 0; i < 8; ++i) {
    int off = wave * 8192 + i * 1024;
    int row = (off >> 8) + (lane >> 4);
    int c = (lane & 15) ^ (row & 15);
    async16(Q + (size_t)(qbase + row) * 128 + c * 8, sKP + off + lane * 16);
  }
  __syncthreads();
  bf16x8 qf[2][4];
#pragma unroll
  for (int mi = 0; mi < 2; ++mi)
#pragma unroll
    for (int ks = 0; ks < 4; ++ks) {
      int m = wave * 32 + mi * 16 + l16;
      qf[mi][ks] = *(const bf16x8*)(sKP + m * 256 + ((((ks << 2) + quad) ^ (m & 15)) << 4));
    }

  f32x4 accO[2][8] = {};
  float mS[2][4], lS[2][4];
#pragma unroll
  for (int a = 0; a < 2; ++a)
#pragma unroll
    for (int r = 0; r < 4; ++r) { mS[a][r] = -INFINITY; lS[a][r] = 0.f; }

  const float scale = 0.088388347648318447f;  // 1/sqrt(128)

  for (int j = 0; j <= qi; ++j) {
    const int tb = j << 7;
    __syncthreads();  // Q-frag reads (j=0) / prev-iter PV reads complete
#pragma unroll
    for (int i = 0; i < 8; ++i) {
      int off = wave * 8192 + i * 1024;
      int row = (off >> 8) + (lane >> 4);
      int c = (lane & 15) ^ (row & 15);
      async16(Kp + (size_t)(tb + row) * 128 + c * 8, sKP + off + lane * 16);
      async16(Vp + (size_t)row * 1024 + tb + c * 8, sV + off + lane * 16);
    }
    __syncthreads();

    // S = Q K^T  (per wave: 32 q-rows x 128 k-cols)
    f32x4 sc[2][8] = {};
#pragma unroll
    for (int ks = 0; ks < 4; ++ks) {
      bf16x8 kf[8];
#pragma unroll
      for (int ni = 0; ni < 8; ++ni) {
        int n = ni * 16 + l16;
        kf[ni] = *(const bf16x8*)(sKP + n * 256 + ((((ks << 2) + quad) ^ (n & 15)) << 4));
      }
#pragma unroll
      for (int mi = 0; mi < 2; ++mi)
#pragma unroll
        for (int ni = 0; ni < 8; ++ni)
          sc[mi][ni] = __builtin_amdgcn_mfma_f32_16x16x32_bf16(qf[mi][ks], kf[ni], sc[mi][ni], 0, 0, 0);
    }

    // online softmax (C-layout: local row = wave*32+mi*16+quad*4+r, local col = ni*16+l16)
    const bool diag = (j == qi);  // tiles aligned: mask only on diagonal tile
#pragma unroll
    for (int mi = 0; mi < 2; ++mi) {
      const int row0 = wave * 32 + mi * 16 + quad * 4;
      float rmax[4];
#pragma unroll
      for (int r = 0; r < 4; ++r) rmax[r] = mS[mi][r];
#pragma unroll
      for (int ni = 0; ni < 8; ++ni) {
        const int col = ni * 16 + l16;
#pragma unroll
        for (int r = 0; r < 4; ++r) {
          float s = sc[mi][ni][r] * scale;
          if (diag && col > row0 + r) s = -INFINITY;
          sc[mi][ni][r] = s;
          rmax[r] = fmaxf(rmax[r], s);
        }
      }
#pragma unroll
      for (int r = 0; r < 4; ++r)
#pragma unroll
        for (int x = 1; x < 16; x <<= 1)
          rmax[r] = fmaxf(rmax[r], __shfl_xor(rmax[r], x));
      float alpha[4];
#pragma unroll
      for (int r = 0; r < 4; ++r) {
        alpha[r] = __expf(mS[mi][r] - rmax[r]);
        mS[mi][r] = rmax[r];
      }
      float rsum[4] = {0.f, 0.f, 0.f, 0.f};
#pragma unroll
      for (int ni = 0; ni < 8; ++ni)
#pragma unroll
        for (int r = 0; r < 4; ++r) {
          float p = __expf(sc[mi][ni][r] - mS[mi][r]);
          sc[mi][ni][r] = p;
          rsum[r] += p;
        }
#pragma unroll
      for (int r = 0; r < 4; ++r) {
#pragma unroll
        for (int x = 1; x < 16; x <<= 1) rsum[r] += __shfl_xor(rsum[r], x);
        lS[mi][r] = lS[mi][r] * alpha[r] + rsum[r];
      }
#pragma unroll
      for (int ni = 0; ni < 8; ++ni)
#pragma unroll
        for (int r = 0; r < 4; ++r) accO[mi][ni][r] *= alpha[r];
    }

    __syncthreads();  // all waves done reading K fragments
    // P (bf16) -> sKP (alias over K); each wave writes its own 32 q-rows
#pragma unroll
    for (int mi = 0; mi < 2; ++mi)
#pragma unroll
      for (int ni = 0; ni < 8; ++ni)
#pragma unroll
        for (int r = 0; r < 4; ++r) {
          int qr = wave * 32 + mi * 16 + quad * 4 + r;
          int kc = ni * 16 + l16;
          *(u16*)(sKP + qr * 256 + (((kc >> 3) ^ (qr & 15)) << 4) + (kc & 7) * 2) =
              f2bf(sc[mi][ni][r]);
        }
    __syncthreads();

    // O += P @ V
#pragma unroll
    for (int ks = 0; ks < 4; ++ks) {
      bf16x8 pf[2], vf[8];
#pragma unroll
      for (int mi = 0; mi < 2; ++mi) {
        int m = wave * 32 + mi * 16 + l16;
        pf[mi] = *(const bf16x8*)(sKP + m * 256 + ((((ks << 2) + quad) ^ (m & 15)) << 4));
      }
#pragma unroll
      for (int ni = 0; ni < 8; ++ni) {
        int n = ni * 16 + l16;
        vf[ni] = *(const bf16x8*)(sV + n * 256 + ((((ks << 2) + quad) ^ (n & 15)) << 4));
      }
#pragma unroll
      for (int mi = 0; mi < 2; ++mi)
#pragma unroll
        for (int ni = 0; ni < 8; ++ni)
          accO[mi][ni] = __builtin_amdgcn_mfma_f32_16x16x32_bf16(pf[mi], vf[ni], accO[mi][ni], 0, 0, 0);
    }
  }

  // epilogue: y[b, t, h*128+d] bf16
  const int b = bh >> 4, h = bh & 15;
#pragma unroll
  for (int mi = 0; mi < 2; ++mi) {
    float inv[4];
#pragma unroll
    for (int r = 0; r < 4; ++r) inv[r] = 1.0f / lS[mi][r];
#pragma unroll
    for (int ni = 0; ni < 8; ++ni)
#pragma unroll
      for (int r = 0; r < 4; ++r) {
        int row = qbase + wave * 32 + mi * 16 + quad * 4 + r;
        int col = (h << 7) + ni * 16 + l16;
        yb[((size_t)(b * 1024 + row) << 11) + col] = f2bf(accO[mi][ni][r] * inv[r]);
      }
  }
}

// ---------------- launch ----------------
extern "C" void kernel_launch(void* const* d_in, const int* in_sizes, int n_in,
                              void* d_out, int out_size, void* d_ws, size_t ws_size,
                              hipStream_t stream) {
  const float* x = (const float*)d_in[0];
  const int* waq = (const int*)d_in[1];
  const float* s_wa = (const float*)d_in[2];
  const int* z_wa = (const int*)d_in[3];
  const int* baq = (const int*)d_in[4];
  const float* s_ba = (const float*)d_in[5];
  const int* z_ba = (const int*)d_in[6];
  const int* wpq = (const int*)d_in[7];
  const float* s_wp = (const float*)d_in[8];
  const int* z_wp = (const int*)d_in[9];
  const int* bpq = (const int*)d_in[10];
  const float* s_bp = (const float*)d_in[11];
  const int* z_bp = (const int*)d_in[12];

  char* ws = (char*)d_ws;
  u16* x_bf  = (u16*)(ws + 0);            // 16 MiB
  u16* wa_bf = (u16*)(ws + 16777216);     // 24 MiB
  u16* wp_bf = (u16*)(ws + 41943040);     // 8 MiB
  u16* qb    = (u16*)(ws + 50331648);     // 16 MiB [B,H,T,D]
  u16* kb    = (u16*)(ws + 67108864);     // 16 MiB [B,H,T,D]
  u16* vT    = (u16*)(ws + 83886080);     // 16 MiB [B,H,D,T]
  u16* yb    = (u16*)(ws + 100663296);    // 16 MiB [B*T, C]

  dequant4<<<12288, 256, 0, stream>>>((const int4*)waq, (ushort4*)wa_bf, 3145728, s_wa, z_wa);
  dequant4<<<4096, 256, 0, stream>>>((const int4*)wpq, (ushort4*)wp_bf, 1048576, s_wp, z_wp);
  castx4<<<8192, 256, 0, stream>>>((const float4*)x, (ushort4*)x_bf, 2097152);

  gemm_bt<0><<<dim3(48, 32), 256, 0, stream>>>(x_bf, wa_bf, 2048, 6144,
                                               baq, s_ba, z_ba, qb, kb, vT, nullptr);

  attn_fwd<<<dim3(8, 64), 256, 0, stream>>>(qb, kb, vT, yb);

  gemm_bt<1><<<dim3(16, 32), 256, 0, stream>>>(yb, wp_bf, 2048, 2048,
                                               bpq, s_bp, z_bp, nullptr, nullptr, nullptr,
                                               (float*)d_out);
}

// Round 5
// 373.137 us; speedup vs baseline: 1.4369x; 1.4369x over previous
//
#include <hip/hip_runtime.h>
#include <stdint.h>
#include <math.h>

typedef unsigned short u16;
typedef __attribute__((ext_vector_type(4))) float f32x4;
typedef __attribute__((ext_vector_type(8))) short bf16x8;

__device__ __forceinline__ u16 f2bf(float f) {
  uint32_t u = __float_as_uint(f);
  u += 0x7FFFu + ((u >> 16) & 1u);
  return (u16)(u >> 16);
}

__device__ __forceinline__ void async16(const void* g, void* l) {
  __builtin_amdgcn_global_load_lds(
      (const __attribute__((address_space(1))) void*)g,
      (__attribute__((address_space(3))) void*)l, 16, 0, 0);
}

// ---------------- dequant / cast ----------------
__global__ void dequant4(const int4* __restrict__ q, ushort4* __restrict__ o, int n4,
                         const float* __restrict__ s, const int* __restrict__ z) {
  int i = blockIdx.x * 256 + threadIdx.x;
  if (i >= n4) return;
  const float sv = s[0];
  const int zv = z[0];
  int4 v = q[i];
  ushort4 r;
  r.x = f2bf(sv * (float)(v.x - zv));
  r.y = f2bf(sv * (float)(v.y - zv));
  r.z = f2bf(sv * (float)(v.z - zv));
  r.w = f2bf(sv * (float)(v.w - zv));
  o[i] = r;
}

__global__ void castx4(const float4* __restrict__ x, ushort4* __restrict__ o, int n4) {
  int i = blockIdx.x * 256 + threadIdx.x;
  if (i >= n4) return;
  float4 v = x[i];
  ushort4 r;
  r.x = f2bf(v.x); r.y = f2bf(v.y); r.z = f2bf(v.z); r.w = f2bf(v.w);
  o[i] = r;
}

// ---------------- BT GEMM: C[M,N] = A[M,K] * B[N,K]^T, 128x128 tile, BK=64 ----------------
template <int EPI>
__global__ __launch_bounds__(256, 2) void gemm_bt(
    const u16* __restrict__ A, const u16* __restrict__ B, int K, int N,
    const int* __restrict__ bq, const float* __restrict__ bs, const int* __restrict__ bz,
    u16* __restrict__ qb, u16* __restrict__ kb, u16* __restrict__ vT,
    float* __restrict__ out) {
  __shared__ uint8_t sA[16384];  // 128 rows x 64 bf16, 8x16B chunks, chunk c stored at c^(row&7)
  __shared__ uint8_t sB[16384];
  const int tid = threadIdx.x;
  const int wave = tid >> 6, lane = tid & 63;
  const int quad = lane >> 4, l16 = lane & 15;
  const int wm = wave >> 1, wn = wave & 1;
  const int Mb = blockIdx.y << 7, Nb = blockIdx.x << 7;

  const u16* ag[4];
  const u16* bg[4];
  int lo[4];
#pragma unroll
  for (int i = 0; i < 4; ++i) {
    int row = wave * 32 + i * 8 + (lane >> 3);
    int c = (lane & 7) ^ (row & 7);
    ag[i] = A + (size_t)(Mb + row) * K + c * 8;
    bg[i] = B + (size_t)(Nb + row) * K + c * 8;
    lo[i] = wave * 4096 + i * 1024 + lane * 16;
  }

  f32x4 acc[4][4] = {};

  for (int kk = 0; kk < K; kk += 64) {
    __syncthreads();
#pragma unroll
    for (int i = 0; i < 4; ++i) {
      async16(ag[i] + kk, sA + lo[i]);
      async16(bg[i] + kk, sB + lo[i]);
    }
    __syncthreads();
#pragma unroll
    for (int ks = 0; ks < 2; ++ks) {
      bf16x8 af[4], bfr[4];
#pragma unroll
      for (int t = 0; t < 4; ++t) {
        int m = wm * 64 + t * 16 + l16;
        af[t] = *(const bf16x8*)(sA + m * 128 + ((((ks << 2) + quad) ^ (m & 7)) << 4));
        int n = wn * 64 + t * 16 + l16;
        bfr[t] = *(const bf16x8*)(sB + n * 128 + ((((ks << 2) + quad) ^ (n & 7)) << 4));
      }
#pragma unroll
      for (int mt = 0; mt < 4; ++mt)
#pragma unroll
        for (int nt = 0; nt < 4; ++nt)
          acc[mt][nt] = __builtin_amdgcn_mfma_f32_16x16x32_bf16(af[mt], bfr[nt], acc[mt][nt], 0, 0, 0);
    }
  }

  const float sbv = bs[0];
  const int zbv = bz[0];
#pragma unroll
  for (int nt = 0; nt < 4; ++nt) {
    const int o = Nb + wn * 64 + nt * 16 + l16;
    const float bias = sbv * (float)(bq[o] - zbv);
    if (EPI == 0) {
      const int which = o >> 11;
      const int cc = o & 2047;
      const int h = cc >> 7, d = cc & 127;
#pragma unroll
      for (int mt = 0; mt < 4; ++mt) {
        const int m0 = Mb + wm * 64 + mt * 16 + quad * 4;
        const int bi = m0 >> 10, t0 = m0 & 1023;
        const size_t bhx = (size_t)bi * 16 + h;
        if (which == 2) {
          ushort4 pv;
          pv.x = f2bf(acc[mt][nt][0] + bias);
          pv.y = f2bf(acc[mt][nt][1] + bias);
          pv.z = f2bf(acc[mt][nt][2] + bias);
          pv.w = f2bf(acc[mt][nt][3] + bias);
          *(ushort4*)(vT + (bhx * 128 + d) * 1024 + t0) = pv;
        } else {
          u16* dst = (which == 0 ? qb : kb) + (bhx * 1024 + t0) * 128 + d;
#pragma unroll
          for (int r = 0; r < 4; ++r) dst[r * 128] = f2bf(acc[mt][nt][r] + bias);
        }
      }
    } else {
#pragma unroll
      for (int mt = 0; mt < 4; ++mt) {
        const int m0 = Mb + wm * 64 + mt * 16 + quad * 4;
#pragma unroll
        for (int r = 0; r < 4; ++r)
          out[(size_t)(m0 + r) * N + o] = acc[mt][nt][r] + bias;
      }
    }
  }
}

// ---------------- flash attention: q-tile 128 (Q in regs), kv-tile 64, LDS 32KB ----------------
// grid = (64 bh, 8 q-idx): same-bh blocks differ by linear stride 64 -> same XCD L2.
__global__ __launch_bounds__(256, 2) void attn_fwd(
    const u16* __restrict__ qg, const u16* __restrict__ kg,
    const u16* __restrict__ vg, u16* __restrict__ yb) {
  __shared__ uint8_t smem[32768];
  uint8_t* sKP = smem;          // K: 64 x 256B (swz ^(row&15)) ; P alias: 128 x 128B (swz ^(row&7))
  uint8_t* sV = smem + 16384;   // V^T: 128 d-rows x 64 t (128B rows, swz ^(d&7))
  const int tid = threadIdx.x;
  const int wave = tid >> 6, lane = tid & 63;
  const int quad = lane >> 4, l16 = lane & 15;
  const int bh = blockIdx.x;
  // causal load balance: adjacent-bh blocks alternate long/short
  const int qi = (bh & 1) ? (7 - (int)blockIdx.y) : (int)blockIdx.y;
  const int qbase = qi << 7;
  const size_t base = (size_t)bh << 17;  // *1024*128
  const u16* Q = qg + base;
  const u16* Kp = kg + base;
  const u16* Vp = vg + base;

  // stage Q tile (32KB over whole smem), then pull fragments to registers
#pragma unroll
  for (int i = 0; i < 8; ++i) {
    int off = wave * 8192 + i * 1024;
    int row = (off >> 8) + quad;
    int c = l16 ^ (row & 15);
    async16(Q + (size_t)(qbase + row) * 128 + c * 8, smem + off + lane * 16);
  }
  __syncthreads();
  bf16x8 qf[2][4];
#pragma unroll
  for (int mi = 0; mi < 2; ++mi)
#pragma unroll
    for (int ks = 0; ks < 4; ++ks) {
      int m = wave * 32 + mi * 16 + l16;
      qf[mi][ks] = *(const bf16x8*)(smem + m * 256 + ((((ks << 2) + quad) ^ (m & 15)) << 4));
    }

  f32x4 accO[2][8] = {};
  float mS[2][4], lS[2][4];
#pragma unroll
  for (int a = 0; a < 2; ++a)
#pragma unroll
    for (int r = 0; r < 4; ++r) { mS[a][r] = -INFINITY; lS[a][r] = 0.f; }

  const float scale = 0.088388347648318447f;  // 1/sqrt(128)
  const int jmax = 2 * qi + 1;

  for (int j = 0; j <= jmax; ++j) {
    const int tb = j << 6;
    __syncthreads();  // qf reads done (j=0) / prev-iter PV reads done
#pragma unroll
    for (int i = 0; i < 4; ++i) {
      int off = wave * 4096 + i * 1024;
      int rowk = (off >> 8) + quad;            // 0..63
      int ck = l16 ^ (rowk & 15);
      async16(Kp + (size_t)(tb + rowk) * 128 + ck * 8, sKP + off + lane * 16);
      int rowd = (off >> 7) + (lane >> 3);     // 0..127
      int cv = (lane & 7) ^ (rowd & 7);
      async16(Vp + (size_t)rowd * 1024 + tb + cv * 8, sV + off + lane * 16);
    }
    __syncthreads();

    // S = Q K^T (per wave: 32 q-rows x 64 k-cols)
    f32x4 sc[2][4] = {};
#pragma unroll
    for (int ks = 0; ks < 4; ++ks) {
      bf16x8 kf[4];
#pragma unroll
      for (int ni = 0; ni < 4; ++ni) {
        int n = ni * 16 + l16;
        kf[ni] = *(const bf16x8*)(sKP + n * 256 + ((((ks << 2) + quad) ^ (n & 15)) << 4));
      }
#pragma unroll
      for (int mi = 0; mi < 2; ++mi)
#pragma unroll
        for (int ni = 0; ni < 4; ++ni)
          sc[mi][ni] = __builtin_amdgcn_mfma_f32_16x16x32_bf16(qf[mi][ks], kf[ni], sc[mi][ni], 0, 0, 0);
    }

    // online softmax (C-layout: row = quad*4+r, col = l16)
    const bool needmask = (tb + 63) > qbase;
#pragma unroll
    for (int mi = 0; mi < 2; ++mi) {
      const int row0 = qbase + wave * 32 + mi * 16 + quad * 4;
      float rmax[4];
#pragma unroll
      for (int r = 0; r < 4; ++r) rmax[r] = mS[mi][r];
#pragma unroll
      for (int ni = 0; ni < 4; ++ni) {
        const int col = tb + ni * 16 + l16;
#pragma unroll
        for (int r = 0; r < 4; ++r) {
          float s = sc[mi][ni][r] * scale;
          if (needmask && col > row0 + r) s = -INFINITY;
          sc[mi][ni][r] = s;
          rmax[r] = fmaxf(rmax[r], s);
        }
      }
#pragma unroll
      for (int r = 0; r < 4; ++r)
#pragma unroll
        for (int x = 1; x < 16; x <<= 1)
          rmax[r] = fmaxf(rmax[r], __shfl_xor(rmax[r], x));
      float alpha[4];
#pragma unroll
      for (int r = 0; r < 4; ++r) {
        alpha[r] = __expf(mS[mi][r] - rmax[r]);
        mS[mi][r] = rmax[r];
      }
      float rsum[4] = {0.f, 0.f, 0.f, 0.f};
#pragma unroll
      for (int ni = 0; ni < 4; ++ni)
#pragma unroll
        for (int r = 0; r < 4; ++r) {
          float p = __expf(sc[mi][ni][r] - mS[mi][r]);
          sc[mi][ni][r] = p;
          rsum[r] += p;
        }
#pragma unroll
      for (int r = 0; r < 4; ++r) {
#pragma unroll
        for (int x = 1; x < 16; x <<= 1) rsum[r] += __shfl_xor(rsum[r], x);
        lS[mi][r] = lS[mi][r] * alpha[r] + rsum[r];
      }
#pragma unroll
      for (int ni = 0; ni < 8; ++ni)
#pragma unroll
        for (int r = 0; r < 4; ++r) accO[mi][ni][r] *= alpha[r];
    }

    __syncthreads();  // all waves done reading K from sKP
    // P (bf16) -> sKP (alias over K); each wave writes its own 32 q-rows
#pragma unroll
    for (int mi = 0; mi < 2; ++mi)
#pragma unroll
      for (int ni = 0; ni < 4; ++ni)
#pragma unroll
        for (int r = 0; r < 4; ++r) {
          int qr = wave * 32 + mi * 16 + quad * 4 + r;
          int kc = ni * 16 + l16;
          *(u16*)(sKP + qr * 128 + (((kc >> 3) ^ (qr & 7)) << 4) + (kc & 7) * 2) =
              f2bf(sc[mi][ni][r]);
        }
    __syncthreads();

    // O += P @ V
#pragma unroll
    for (int ks = 0; ks < 2; ++ks) {
      bf16x8 pf[2], vf[8];
#pragma unroll
      for (int mi = 0; mi < 2; ++mi) {
        int m = wave * 32 + mi * 16 + l16;
        pf[mi] = *(const bf16x8*)(sKP + m * 128 + ((((ks << 2) + quad) ^ (m & 7)) << 4));
      }
#pragma unroll
      for (int ni = 0; ni < 8; ++ni) {
        int n = ni * 16 + l16;
        vf[ni] = *(const bf16x8*)(sV + n * 128 + ((((ks << 2) + quad) ^ (n & 7)) << 4));
      }
#pragma unroll
      for (int mi = 0; mi < 2; ++mi)
#pragma unroll
        for (int ni = 0; ni < 8; ++ni)
          accO[mi][ni] = __builtin_amdgcn_mfma_f32_16x16x32_bf16(pf[mi], vf[ni], accO[mi][ni], 0, 0, 0);
    }
  }

  // epilogue: y[b, t, h*128+d] bf16
  const int b = bh >> 4, h = bh & 15;
#pragma unroll
  for (int mi = 0; mi < 2; ++mi) {
    float inv[4];
#pragma unroll
    for (int r = 0; r < 4; ++r) inv[r] = 1.0f / lS[mi][r];
#pragma unroll
    for (int ni = 0; ni < 8; ++ni)
#pragma unroll
      for (int r = 0; r < 4; ++r) {
        int row = qbase + wave * 32 + mi * 16 + quad * 4 + r;
        int col = (h << 7) + ni * 16 + l16;
        yb[((size_t)(b * 1024 + row) << 11) + col] = f2bf(accO[mi][ni][r] * inv[r]);
      }
  }
}

// ---------------- launch ----------------
extern "C" void kernel_launch(void* const* d_in, const int* in_sizes, int n_in,
                              void* d_out, int out_size, void* d_ws, size_t ws_size,
                              hipStream_t stream) {
  const float* x = (const float*)d_in[0];
  const int* waq = (const int*)d_in[1];
  const float* s_wa = (const float*)d_in[2];
  const int* z_wa = (const int*)d_in[3];
  const int* baq = (const int*)d_in[4];
  const float* s_ba = (const float*)d_in[5];
  const int* z_ba = (const int*)d_in[6];
  const int* wpq = (const int*)d_in[7];
  const float* s_wp = (const float*)d_in[8];
  const int* z_wp = (const int*)d_in[9];
  const int* bpq = (const int*)d_in[10];
  const float* s_bp = (const float*)d_in[11];
  const int* z_bp = (const int*)d_in[12];

  char* ws = (char*)d_ws;
  u16* x_bf  = (u16*)(ws + 0);            // 16 MiB
  u16* wa_bf = (u16*)(ws + 16777216);     // 24 MiB
  u16* wp_bf = (u16*)(ws + 41943040);     // 8 MiB
  u16* qb    = (u16*)(ws + 50331648);     // 16 MiB [B,H,T,D]
  u16* kb    = (u16*)(ws + 67108864);     // 16 MiB [B,H,T,D]
  u16* vT    = (u16*)(ws + 83886080);     // 16 MiB [B,H,D,T]
  u16* yb    = (u16*)(ws + 100663296);    // 16 MiB [B*T, C]

  dequant4<<<12288, 256, 0, stream>>>((const int4*)waq, (ushort4*)wa_bf, 3145728, s_wa, z_wa);
  dequant4<<<4096, 256, 0, stream>>>((const int4*)wpq, (ushort4*)wp_bf, 1048576, s_wp, z_wp);
  castx4<<<8192, 256, 0, stream>>>((const float4*)x, (ushort4*)x_bf, 2097152);

  gemm_bt<0><<<dim3(48, 32), 256, 0, stream>>>(x_bf, wa_bf, 2048, 6144,
                                               baq, s_ba, z_ba, qb, kb, vT, nullptr);

  attn_fwd<<<dim3(64, 8), 256, 0, stream>>>(qb, kb, vT, yb);

  gemm_bt<1><<<dim3(16, 32), 256, 0, stream>>>(yb, wp_bf, 2048, 2048,
                                               bpq, s_bp, z_bp, nullptr, nullptr, nullptr,
                                               (float*)d_out);
}